// Round 9
// baseline (789.753 us; speedup 1.0000x reference)
//
#include <hip/hip_runtime.h>
#include <math.h>

#define NN 50000
#define EE 800000
#define OO 4
#define CC 64
#define KDD 16
#define KEYDD 128
#define CH 16  // gather window per chunk (pipelined across chunks)

// Full-wave (64-lane) sum via DPP (pure VALU, no LDS/ds_bpermute).
__device__ __forceinline__ float wave_red_sum(float v) {
  int x;
  x = __builtin_amdgcn_update_dpp(0, __float_as_int(v), 0x111, 0xf, 0xf, false);
  v += __int_as_float(x);
  x = __builtin_amdgcn_update_dpp(0, __float_as_int(v), 0x112, 0xf, 0xf, false);
  v += __int_as_float(x);
  x = __builtin_amdgcn_update_dpp(0, __float_as_int(v), 0x114, 0xf, 0xf, false);
  v += __int_as_float(x);
  x = __builtin_amdgcn_update_dpp(0, __float_as_int(v), 0x118, 0xf, 0xf, false);
  v += __int_as_float(x);
  x = __builtin_amdgcn_update_dpp(0, __float_as_int(v), 0x142, 0xa, 0xf, false);
  v += __int_as_float(x);
  x = __builtin_amdgcn_update_dpp(0, __float_as_int(v), 0x143, 0xc, 0xf, false);
  v += __int_as_float(x);
  return __int_as_float(__builtin_amdgcn_readlane(__float_as_int(v), 63));
}

// bare v_exp_f32: D = 2^x  (softmax runs in log2 domain)
__device__ __forceinline__ float exp2_fast(float x) {
  float r;
  asm("v_exp_f32 %0, %1" : "=v"(r) : "v"(x));
  return r;
}

// P0 (blocks 0..15): Mt[c2*64+c1] = sum_k keyW[k,c1]*qryW[k,c2] (transposed so
// mega's per-c2 read is one coalesced 256B segment). Block 16: aVec/bVec/c0/fk
// (fk pre-scaled by 0.25).
__global__ void prep_kernel(const float* __restrict__ keyW, const float* __restrict__ keyB,
                            const float* __restrict__ qryW, const float* __restrict__ qryB,
                            const float* __restrict__ fkb, const float* __restrict__ fkw,
                            float* __restrict__ Mt, float* __restrict__ aVec,
                            float* __restrict__ bVec, float* __restrict__ c0,
                            float* __restrict__ fk) {
  __shared__ float qw[KEYDD * CC];   // 32 KB
  __shared__ float kws[KEYDD * 4];   // 2 KB
  int t = threadIdx.x, b = blockIdx.x;
  if (b < 16) {
    for (int i = t; i < KEYDD * CC; i += 256) qw[i] = qryW[i];
    for (int i = t; i < KEYDD * 4; i += 256) {
      int k = i >> 2, c1l = i & 3;
      kws[i] = keyW[k * CC + b * 4 + c1l];
    }
    __syncthreads();
    int c1l = t >> 6, c2 = t & 63;
    float s = 0.f;
    #pragma unroll 8
    for (int k = 0; k < KEYDD; ++k)
      s = fmaf(kws[k * 4 + c1l], qw[k * CC + c2], s);
    Mt[c2 * CC + b * 4 + c1l] = s;
  } else {
    if (t < CC) {
      float sa = 0.f, sb = 0.f;
      for (int k = 0; k < KEYDD; ++k) {
        sa = fmaf(keyB[k], qryW[k * CC + t], sa);
        sb = fmaf(qryB[k], keyW[k * CC + t], sb);
      }
      aVec[t] = sa; bVec[t] = sb;
    }
    if (t == 0) {
      float s = 0.f;
      for (int k = 0; k < KEYDD; ++k) s = fmaf(keyB[k], qryB[k], s);
      c0[0] = s;
    }
    for (int idx = t; idx < OO * OO * CC; idx += 256) {
      int p = idx >> 8, rem = idx & 255;
      int o = rem >> 6, c = rem & 63;
      float s = 0.f;
      #pragma unroll
      for (int kd = 0; kd < KDD; ++kd)
        s = fmaf(fkb[(p * OO + o) * KDD + kd], fkw[c * KDD + kd], s);
      fk[idx] = 0.25f * s;  // fold the 1/O normalization here
    }
  }
}

// K2a: CSR degree counts
__global__ void count_kernel(const int* __restrict__ ei, int* __restrict__ counts) {
  int e = blockIdx.x * 256 + threadIdx.x;
  if (e < EE) atomicAdd(&counts[ei[EE + e]], 1);
}

// K2b: single-block chunked exclusive scan
__global__ void scan_kernel(const int* __restrict__ counts, int* __restrict__ offsets, int n) {
  __shared__ int sums[1024];
  int t = threadIdx.x;
  int chunk = (n + 1023) >> 10;
  int begin = t * chunk;
  int finish = min(begin + chunk, n);
  int s = 0;
  for (int i = begin; i < finish; ++i) s += counts[i];
  sums[t] = s;
  __syncthreads();
  for (int off = 1; off < 1024; off <<= 1) {
    int v = sums[t];
    int w = (t >= off) ? sums[t - off] : 0;
    __syncthreads();
    sums[t] = v + w;
    __syncthreads();
  }
  int excl = (t == 0) ? 0 : sums[t - 1];
  for (int i = begin; i < finish; ++i) {
    offsets[i] = excl;
    excl += counts[i];
  }
  if (t == 1023) offsets[n] = excl;
}

// K2c: fill CSR as packed (src<<32 | eid) pairs; reuses counts as cursor.
__global__ void fill_kernel(const int* __restrict__ ei, const int* __restrict__ offsets,
                            int* __restrict__ counts, long long* __restrict__ pairs) {
  int e = blockIdx.x * 256 + threadIdx.x;
  if (e < EE) {
    int d = ei[EE + e];
    int r = atomicSub(&counts[d], 1) - 1;
    int pos = offsets[d] + r;
    pairs[pos] = ((long long)ei[e] << 32) | (unsigned)e;
  }
}

// kv = dot16(kb[ej, o, :], kW[c, :])  — kb slice wave-uniform (SMEM/s_load path)
__device__ __forceinline__ float kv_dot(const float* __restrict__ kb, int ej, int obase,
                                        float4 kw0, float4 kw1, float4 kw2, float4 kw3) {
  const float4* bp = reinterpret_cast<const float4*>(kb + ej * (OO * KDD) + obase);
  float4 b0 = bp[0], b1 = bp[1], b2 = bp[2], b3 = bp[3];
  float kva = 0.f, kvb = 0.f;
  kva = fmaf(b0.x, kw0.x, kva); kva = fmaf(b0.y, kw0.y, kva);
  kva = fmaf(b0.z, kw0.z, kva); kva = fmaf(b0.w, kw0.w, kva);
  kva = fmaf(b1.x, kw1.x, kva); kva = fmaf(b1.y, kw1.y, kva);
  kva = fmaf(b1.z, kw1.z, kva); kva = fmaf(b1.w, kw1.w, kva);
  kvb = fmaf(b2.x, kw2.x, kvb); kvb = fmaf(b2.y, kw2.y, kvb);
  kvb = fmaf(b2.z, kw2.z, kvb); kvb = fmaf(b2.w, kw2.w, kvb);
  kvb = fmaf(b3.x, kw3.x, kvb); kvb = fmaf(b3.y, kw3.y, kvb);
  kvb = fmaf(b3.z, kw3.z, kvb); kvb = fmaf(b3.w, kw3.w, kvb);
  return kva + kvb;
}

// K3: MEGA — per node; fused ub, then wave=o owns its (n,o) softmax+aggregation
// end-to-end. TWO-STAGE SOFTWARE PIPELINE across 16-edge chunks: gathers for
// chunk i+1 issue BEFORE compute of chunk i (ping-pong xvA/xvB, static indices
// only), pairs prefetched one chunk further ahead. sched_barrier(0) pins the
// gather block ahead of compute so the scheduler can't sink the loads to shrink
// VGPR (R8: it did exactly that — VGPR 32, MLP destroyed, perf flat).
// Compute in 4-edge sub-blocks (Poisson(16) degrees: 16-pad wastes 46%, 4-pad 12%).
// NOTE: no min-waves launch_bounds — (256,8) caused VGPR spill (R4: 4x regress).
__global__ __launch_bounds__(256) void mega_kernel(
    const float* __restrict__ x, const float* __restrict__ Mt,
    const float* __restrict__ aVec, const float* __restrict__ bVec,
    const float* __restrict__ c0p, const float* __restrict__ kb,
    const float* __restrict__ kW, const int* __restrict__ offsets,
    const long long* __restrict__ pairs, const float* __restrict__ fkg,
    const float* __restrict__ bias, float* __restrict__ out) {
  __shared__ float xs[OO * CC];
  __shared__ float x1[OO * CC];
  int n = blockIdx.x;
  int t = threadIdx.x;
  int o = __builtin_amdgcn_readfirstlane(t >> 6);
  int c = t & 63;
  const float scale2 = 0.12751541050862828f;  // (1/sqrt(128)) * log2(e)
  int js = offsets[n], je = offsets[n + 1];
  int deg = je - js;

  float xown = x[(size_t)n * (OO * CC) + t];
  xs[t] = xown;
  __syncthreads();

  int lane16 = c & 15;
  long long pr_a = 0;
  if (deg > 0) pr_a = pairs[js + min(lane16, deg - 1)];  // chunk-0 head, early

  // ub = Mt^T x + bVec (independent of pr_a -> hides the pairs-load latency)
  float ubr = 0.f;
  #pragma unroll 8
  for (int c2 = 0; c2 < CC; ++c2)
    ubr = fmaf(Mt[c2 * CC + c], xs[o * CC + c2], ubr);
  ubr += bVec[c];
  float base2 = (wave_red_sum(aVec[c] * xown) + c0p[0]) * scale2;

  const float4* kwp = reinterpret_cast<const float4*>(kW + c * KDD);
  float4 kw0 = kwp[0], kw1 = kwp[1], kw2 = kwp[2], kw3 = kwp[3];
  int obase = o * KDD;

  float m2 = -INFINITY, S = 0.f, acc = 0.f;

  #define GATHER(XV, PR)                                            \
  {                                                                 \
    int s_hi = (int)((PR) >> 32);                                   \
    _Pragma("unroll")                                               \
    for (int j = 0; j < CH; ++j) {                                  \
      int sj = __builtin_amdgcn_readlane(s_hi, j);                  \
      XV[j] = x[(size_t)(sj * OO + o) * CC + c];                    \
    }                                                               \
  }

  #define SUB4(XV, EV, J0, CL)                                      \
  {                                                                 \
    float kv0 = kv_dot(kb, __builtin_amdgcn_readlane(EV, (J0) + 0), obase, kw0, kw1, kw2, kw3); \
    float kv1 = kv_dot(kb, __builtin_amdgcn_readlane(EV, (J0) + 1), obase, kw0, kw1, kw2, kw3); \
    float kv2 = kv_dot(kb, __builtin_amdgcn_readlane(EV, (J0) + 2), obase, kw0, kw1, kw2, kw3); \
    float kv3 = kv_dot(kb, __builtin_amdgcn_readlane(EV, (J0) + 3), obase, kw0, kw1, kw2, kw3); \
    float p0 = wave_red_sum(XV[(J0) + 0] * ubr);                    \
    float p1 = wave_red_sum(XV[(J0) + 1] * ubr);                    \
    float p2 = wave_red_sum(XV[(J0) + 2] * ubr);                    \
    float p3 = wave_red_sum(XV[(J0) + 3] * ubr);                    \
    float l0 = ((J0) + 0 < (CL)) ? fmaf(p0, scale2, base2) : -INFINITY; \
    float l1 = ((J0) + 1 < (CL)) ? fmaf(p1, scale2, base2) : -INFINITY; \
    float l2 = ((J0) + 2 < (CL)) ? fmaf(p2, scale2, base2) : -INFINITY; \
    float l3 = ((J0) + 3 < (CL)) ? fmaf(p3, scale2, base2) : -INFINITY; \
    float cm = fmaxf(fmaxf(l0, l1), fmaxf(l2, l3));                 \
    float mn = fmaxf(m2, cm);                                       \
    float rsc = exp2_fast(m2 - mn);                                 \
    S *= rsc; acc *= rsc; m2 = mn;                                  \
    float ev0 = exp2_fast(l0 - m2);                                 \
    float ev1 = exp2_fast(l1 - m2);                                 \
    float ev2 = exp2_fast(l2 - m2);                                 \
    float ev3 = exp2_fast(l3 - m2);                                 \
    S += ev0 + ev1 + ev2 + ev3;                                     \
    acc = fmaf(ev0 * kv0, XV[(J0) + 0], acc);                       \
    acc = fmaf(ev1 * kv1, XV[(J0) + 1], acc);                       \
    acc = fmaf(ev2 * kv2, XV[(J0) + 2], acc);                       \
    acc = fmaf(ev3 * kv3, XV[(J0) + 3], acc);                       \
  }

  #define COMPUTE(XV, EV, CL)                                       \
    SUB4(XV, EV, 0, CL)                                             \
    if ((CL) > 4)  SUB4(XV, EV, 4, CL)                              \
    if ((CL) > 8)  SUB4(XV, EV, 8, CL)                              \
    if ((CL) > 12) SUB4(XV, EV, 12, CL)

  if (deg > 0) {
    float xvA[CH], xvB[CH];
    // prologue: gather chunk 0, prefetch pairs for chunk 1
    GATHER(xvA, pr_a)
    long long pr_b = 0;
    if (CH < deg) pr_b = pairs[js + CH + min(lane16, deg - CH - 1)];
    __builtin_amdgcn_sched_barrier(0);

    int cs = 0;
    while (true) {
      // ---- chunk cs (xvA, pr_a); fill xvB for cs+CH, prefetch pairs cs+2CH into pr_a
      int e_cur = (int)((unsigned long long)pr_a & 0xffffffffu);
      int cl = deg - cs; if (cl > CH) cl = CH;
      bool hasNext = (cs + CH) < deg;
      if (hasNext) {
        GATHER(xvB, pr_b)
        int ns2 = cs + 2 * CH;
        if (ns2 < deg) pr_a = pairs[js + ns2 + min(lane16, deg - ns2 - 1)];
        __builtin_amdgcn_sched_barrier(0);
      }
      COMPUTE(xvA, e_cur, cl)
      if (!hasNext) break;
      cs += CH;
      // ---- chunk cs (xvB, pr_b); fill xvA for cs+CH, prefetch pairs cs+2CH into pr_b
      e_cur = (int)((unsigned long long)pr_b & 0xffffffffu);
      cl = deg - cs; if (cl > CH) cl = CH;
      hasNext = (cs + CH) < deg;
      if (hasNext) {
        GATHER(xvA, pr_a)
        int ns2 = cs + 2 * CH;
        if (ns2 < deg) pr_b = pairs[js + ns2 + min(lane16, deg - ns2 - 1)];
        __builtin_amdgcn_sched_barrier(0);
      }
      COMPUTE(xvB, e_cur, cl)
      if (!hasNext) break;
      cs += CH;
    }
  }
  #undef COMPUTE
  #undef SUB4
  #undef GATHER

  float invd = 1.0f / (S + 1e-6f);
  x1[t] = acc * invd;
  __syncthreads();
  // fiber mix: out[n,p=o,c] = sum_oo x1[oo,c]*fk[o,oo,c] + bias[c]  (0.25 in fk)
  float s2s = 0.f;
  #pragma unroll
  for (int oo = 0; oo < OO; ++oo)
    s2s = fmaf(x1[oo * CC + c], fkg[o * (OO * CC) + oo * CC + c], s2s);
  out[(size_t)n * (OO * CC) + t] = s2s + bias[c];
}

extern "C" void kernel_launch(void* const* d_in, const int* in_sizes, int n_in,
                              void* d_out, int out_size, void* d_ws, size_t ws_size,
                              hipStream_t stream) {
  const float* x    = (const float*)d_in[0];
  const float* kb   = (const float*)d_in[1];
  const float* fkb  = (const float*)d_in[2];
  const int*   ei   = (const int*)d_in[3];
  const float* kW   = (const float*)d_in[4];
  const float* fkW  = (const float*)d_in[5];
  const float* keyW = (const float*)d_in[6];
  const float* keyB = (const float*)d_in[7];
  const float* qryW = (const float*)d_in[8];
  const float* qryB = (const float*)d_in[9];
  const float* bias = (const float*)d_in[10];
  float* out = (float*)d_out;

  float* wsf  = (float*)d_ws;
  float* Mt   = wsf;                          // 4096
  float* aVec = Mt + 4096;                    // 64
  float* bVec = aVec + 64;                    // 64
  float* c0   = bVec + 64;                    // 1 (+63 pad)
  float* fk   = c0 + 64;                      // 1024
  // total 5312 floats = 21248 B (8B-aligned)
  long long* pairs = (long long*)(fk + 1024);   // EE * 8B
  int* counts    = (int*)(pairs + EE);          // 50000
  int* offsets   = counts + NN;                 // 50001

  hipMemsetAsync(counts, 0, (size_t)NN * sizeof(int), stream);

  prep_kernel<<<17, 256, 0, stream>>>(keyW, keyB, qryW, qryB, fkb, fkW, Mt, aVec, bVec, c0, fk);
  count_kernel<<<(EE + 255) / 256, 256, 0, stream>>>(ei, counts);
  scan_kernel<<<1, 1024, 0, stream>>>(counts, offsets, NN);
  fill_kernel<<<(EE + 255) / 256, 256, 0, stream>>>(ei, offsets, counts, pairs);
  mega_kernel<<<NN, 256, 0, stream>>>(x, Mt, aVec, bVec, c0, kb, kW, offsets, pairs,
                                      fk, bias, out);
}

// Round 10
// 535.093 us; speedup vs baseline: 1.4759x; 1.4759x over previous
//
#include <hip/hip_runtime.h>
#include <math.h>

#define NN 50000
#define EE 800000
#define OO 4
#define CC 64
#define KDD 16
#define KEYDD 128
#define CH 16  // gather window per chunk

// Full-wave (64-lane) sum via DPP builtins (prologue only; compiler handles hazards)
__device__ __forceinline__ float wave_red_sum(float v) {
  int x;
  x = __builtin_amdgcn_update_dpp(0, __float_as_int(v), 0x111, 0xf, 0xf, false);
  v += __int_as_float(x);
  x = __builtin_amdgcn_update_dpp(0, __float_as_int(v), 0x112, 0xf, 0xf, false);
  v += __int_as_float(x);
  x = __builtin_amdgcn_update_dpp(0, __float_as_int(v), 0x114, 0xf, 0xf, false);
  v += __int_as_float(x);
  x = __builtin_amdgcn_update_dpp(0, __float_as_int(v), 0x118, 0xf, 0xf, false);
  v += __int_as_float(x);
  x = __builtin_amdgcn_update_dpp(0, __float_as_int(v), 0x142, 0xa, 0xf, false);
  v += __int_as_float(x);
  x = __builtin_amdgcn_update_dpp(0, __float_as_int(v), 0x143, 0xc, 0xf, false);
  v += __int_as_float(x);
  return __int_as_float(__builtin_amdgcn_readlane(__float_as_int(v), 63));
}

// bare v_exp_f32: D = 2^x  (softmax runs in log2 domain)
__device__ __forceinline__ float exp2_fast(float x) {
  float r;
  asm("v_exp_f32 %0, %1" : "=v"(r) : "v"(x));
  return r;
}

// Batched reduction of FOUR 64-lane vectors -> four wave-uniform sums.
// Step 1: permlane32_swap folds {q0,q1}->ra (lo=q0 xor32-partial, hi=q1) and
// {q2,q3}->rb. Step 2: one asm block of 10 v_add_f32_dpp, ALTERNATING the two
// independent chains so each DPP's 2-wait-state read-after-VALU-write hazard is
// covered by the other chain's instruction (wave64 VALU = 2cy). s_nop 1 guards
// block entry. Totals land at lanes 31/63 of each chain.
__device__ __forceinline__ void red4(float q0, float q1, float q2, float q3,
                                     float& p0, float& p1, float& p2, float& p3) {
  asm("s_nop 1\n\tv_permlane32_swap_b32 %0, %1" : "+v"(q0), "+v"(q1));
  float ra = q0 + q1;
  asm("s_nop 1\n\tv_permlane32_swap_b32 %0, %1" : "+v"(q2), "+v"(q3));
  float rb = q2 + q3;
  asm("s_nop 1\n\t"
      "v_add_f32_dpp %0, %0, %0 row_shr:1 row_mask:0xf bank_mask:0xf bound_ctrl:0\n\t"
      "v_add_f32_dpp %1, %1, %1 row_shr:1 row_mask:0xf bank_mask:0xf bound_ctrl:0\n\t"
      "v_add_f32_dpp %0, %0, %0 row_shr:2 row_mask:0xf bank_mask:0xf bound_ctrl:0\n\t"
      "v_add_f32_dpp %1, %1, %1 row_shr:2 row_mask:0xf bank_mask:0xf bound_ctrl:0\n\t"
      "v_add_f32_dpp %0, %0, %0 row_shr:4 row_mask:0xf bank_mask:0xf bound_ctrl:0\n\t"
      "v_add_f32_dpp %1, %1, %1 row_shr:4 row_mask:0xf bank_mask:0xf bound_ctrl:0\n\t"
      "v_add_f32_dpp %0, %0, %0 row_shr:8 row_mask:0xf bank_mask:0xf bound_ctrl:0\n\t"
      "v_add_f32_dpp %1, %1, %1 row_shr:8 row_mask:0xf bank_mask:0xf bound_ctrl:0\n\t"
      "v_add_f32_dpp %0, %0, %0 row_bcast:15 row_mask:0xa bank_mask:0xf bound_ctrl:0\n\t"
      "v_add_f32_dpp %1, %1, %1 row_bcast:15 row_mask:0xa bank_mask:0xf bound_ctrl:0\n\t"
      "s_nop 0"
      : "+v"(ra), "+v"(rb));
  p0 = __int_as_float(__builtin_amdgcn_readlane(__float_as_int(ra), 31));
  p1 = __int_as_float(__builtin_amdgcn_readlane(__float_as_int(ra), 63));
  p2 = __int_as_float(__builtin_amdgcn_readlane(__float_as_int(rb), 31));
  p3 = __int_as_float(__builtin_amdgcn_readlane(__float_as_int(rb), 63));
}

// P0 (blocks 0..15): Mt[c2*64+c1] = sum_k keyW[k,c1]*qryW[k,c2] (transposed so
// mega's per-c2 read is one coalesced 256B segment). Block 16: aVec/bVec/c0/fk
// (fk pre-scaled by 0.25).
__global__ void prep_kernel(const float* __restrict__ keyW, const float* __restrict__ keyB,
                            const float* __restrict__ qryW, const float* __restrict__ qryB,
                            const float* __restrict__ fkb, const float* __restrict__ fkw,
                            float* __restrict__ Mt, float* __restrict__ aVec,
                            float* __restrict__ bVec, float* __restrict__ c0,
                            float* __restrict__ fk) {
  __shared__ float qw[KEYDD * CC];   // 32 KB
  __shared__ float kws[KEYDD * 4];   // 2 KB
  int t = threadIdx.x, b = blockIdx.x;
  if (b < 16) {
    for (int i = t; i < KEYDD * CC; i += 256) qw[i] = qryW[i];
    for (int i = t; i < KEYDD * 4; i += 256) {
      int k = i >> 2, c1l = i & 3;
      kws[i] = keyW[k * CC + b * 4 + c1l];
    }
    __syncthreads();
    int c1l = t >> 6, c2 = t & 63;
    float s = 0.f;
    #pragma unroll 8
    for (int k = 0; k < KEYDD; ++k)
      s = fmaf(kws[k * 4 + c1l], qw[k * CC + c2], s);
    Mt[c2 * CC + b * 4 + c1l] = s;
  } else {
    if (t < CC) {
      float sa = 0.f, sb = 0.f;
      for (int k = 0; k < KEYDD; ++k) {
        sa = fmaf(keyB[k], qryW[k * CC + t], sa);
        sb = fmaf(qryB[k], keyW[k * CC + t], sb);
      }
      aVec[t] = sa; bVec[t] = sb;
    }
    if (t == 0) {
      float s = 0.f;
      for (int k = 0; k < KEYDD; ++k) s = fmaf(keyB[k], qryB[k], s);
      c0[0] = s;
    }
    for (int idx = t; idx < OO * OO * CC; idx += 256) {
      int p = idx >> 8, rem = idx & 255;
      int o = rem >> 6, c = rem & 63;
      float s = 0.f;
      #pragma unroll
      for (int kd = 0; kd < KDD; ++kd)
        s = fmaf(fkb[(p * OO + o) * KDD + kd], fkw[c * KDD + kd], s);
      fk[idx] = 0.25f * s;  // fold the 1/O normalization here
    }
  }
}

// K2a: CSR degree counts
__global__ void count_kernel(const int* __restrict__ ei, int* __restrict__ counts) {
  int e = blockIdx.x * 256 + threadIdx.x;
  if (e < EE) atomicAdd(&counts[ei[EE + e]], 1);
}

// K2b: single-block chunked exclusive scan
__global__ void scan_kernel(const int* __restrict__ counts, int* __restrict__ offsets, int n) {
  __shared__ int sums[1024];
  int t = threadIdx.x;
  int chunk = (n + 1023) >> 10;
  int begin = t * chunk;
  int finish = min(begin + chunk, n);
  int s = 0;
  for (int i = begin; i < finish; ++i) s += counts[i];
  sums[t] = s;
  __syncthreads();
  for (int off = 1; off < 1024; off <<= 1) {
    int v = sums[t];
    int w = (t >= off) ? sums[t - off] : 0;
    __syncthreads();
    sums[t] = v + w;
    __syncthreads();
  }
  int excl = (t == 0) ? 0 : sums[t - 1];
  for (int i = begin; i < finish; ++i) {
    offsets[i] = excl;
    excl += counts[i];
  }
  if (t == 1023) offsets[n] = excl;
}

// K2c: fill CSR as packed (src<<32 | eid) pairs; reuses counts as cursor.
__global__ void fill_kernel(const int* __restrict__ ei, const int* __restrict__ offsets,
                            int* __restrict__ counts, long long* __restrict__ pairs) {
  int e = blockIdx.x * 256 + threadIdx.x;
  if (e < EE) {
    int d = ei[EE + e];
    int r = atomicSub(&counts[d], 1) - 1;
    int pos = offsets[d] + r;
    pairs[pos] = ((long long)ei[e] << 32) | (unsigned)e;
  }
}

// kv = dot16(kb[ej, o, :], kW[c, :])  — kb slice wave-uniform (SMEM/s_load path)
__device__ __forceinline__ float kv_dot(const float* __restrict__ kb, int ej, int obase,
                                        float4 kw0, float4 kw1, float4 kw2, float4 kw3) {
  const float4* bp = reinterpret_cast<const float4*>(kb + ej * (OO * KDD) + obase);
  float4 b0 = bp[0], b1 = bp[1], b2 = bp[2], b3 = bp[3];
  float kva = 0.f, kvb = 0.f;
  kva = fmaf(b0.x, kw0.x, kva); kva = fmaf(b0.y, kw0.y, kva);
  kva = fmaf(b0.z, kw0.z, kva); kva = fmaf(b0.w, kw0.w, kva);
  kva = fmaf(b1.x, kw1.x, kva); kva = fmaf(b1.y, kw1.y, kva);
  kva = fmaf(b1.z, kw1.z, kva); kva = fmaf(b1.w, kw1.w, kva);
  kvb = fmaf(b2.x, kw2.x, kvb); kvb = fmaf(b2.y, kw2.y, kvb);
  kvb = fmaf(b2.z, kw2.z, kvb); kvb = fmaf(b2.w, kw2.w, kvb);
  kvb = fmaf(b3.x, kw3.x, kvb); kvb = fmaf(b3.y, kw3.y, kvb);
  kvb = fmaf(b3.z, kw3.z, kvb); kvb = fmaf(b3.w, kw3.w, kvb);
  return kva + kvb;
}

// K3: MEGA — per node; fused ub, wave=o owns its (n,o) softmax+aggregation
// end-to-end, barrier-free edge loop (R8 structure: no sched_barrier pipeline —
// R9 showed pinned prefetch entangles the in-order vmcnt queue and collapses
// occupancy; TLP across ~7 resident waves is the latency hider).
// Changes vs R8: 4-edge sub-blocks (Poisson(16) degrees: pad-to-8 wastes 25%,
// pad-to-4 12%) and batched red4 logit reduction (~24 slots vs ~56 per 4 edges).
// NOTE: no min-waves launch_bounds — (256,8) caused VGPR spill (R4: 4x regress).
__global__ __launch_bounds__(256) void mega_kernel(
    const float* __restrict__ x, const float* __restrict__ Mt,
    const float* __restrict__ aVec, const float* __restrict__ bVec,
    const float* __restrict__ c0p, const float* __restrict__ kb,
    const float* __restrict__ kW, const int* __restrict__ offsets,
    const long long* __restrict__ pairs, const float* __restrict__ fkg,
    const float* __restrict__ bias, float* __restrict__ out) {
  __shared__ float xs[OO * CC];
  __shared__ float x1[OO * CC];
  int n = blockIdx.x;
  int t = threadIdx.x;
  int o = __builtin_amdgcn_readfirstlane(t >> 6);
  int c = t & 63;
  const float scale2 = 0.12751541050862828f;  // (1/sqrt(128)) * log2(e)
  int js = offsets[n], je = offsets[n + 1];
  int deg = je - js;

  float xown = x[(size_t)n * (OO * CC) + t];
  xs[t] = xown;
  __syncthreads();

  int lane16 = c & 15;
  long long pr = 0;
  if (deg > 0) pr = pairs[js + min(lane16, deg - 1)];  // chunk-0 head, in flight early

  // ub = Mt^T x + bVec (independent of pr -> hides the pairs-load latency)
  float ubr = 0.f;
  #pragma unroll 8
  for (int c2 = 0; c2 < CC; ++c2)
    ubr = fmaf(Mt[c2 * CC + c], xs[o * CC + c2], ubr);
  ubr += bVec[c];
  float base2 = (wave_red_sum(aVec[c] * xown) + c0p[0]) * scale2;

  const float4* kwp = reinterpret_cast<const float4*>(kW + c * KDD);
  float4 kw0 = kwp[0], kw1 = kwp[1], kw2 = kwp[2], kw3 = kwp[3];
  int obase = o * KDD;

  float m2 = -INFINITY, S = 0.f, acc = 0.f;

  for (int cs = 0; cs < deg; cs += CH) {
    int cl = deg - cs; if (cl > CH) cl = CH;  // wave-uniform
    int e_v = (int)((unsigned long long)pr & 0xffffffffu);
    int s_v = (int)(pr >> 32);
    float xv[CH];
    // 1) x-row gathers (uniform row base via readlane; compiler schedules)
    #pragma unroll
    for (int j = 0; j < CH; ++j) {
      int sj = __builtin_amdgcn_readlane(s_v, j);
      xv[j] = x[(size_t)(sj * OO + o) * CC + c];
    }
    // 2) prefetch next chunk's pairs (head of next dependency chain)
    int ns = cs + CH;
    if (ns < deg) {
      int ncl = deg - ns;
      pr = pairs[js + ns + min(lane16, ncl - 1)];
    }
    // 3) compute in 4-edge sub-blocks (tail waste ~12% vs 25% at 8)
    #define SUB4(J0)                                                           \
    {                                                                          \
      float kv0 = kv_dot(kb, __builtin_amdgcn_readlane(e_v, (J0) + 0), obase, kw0, kw1, kw2, kw3); \
      float kv1 = kv_dot(kb, __builtin_amdgcn_readlane(e_v, (J0) + 1), obase, kw0, kw1, kw2, kw3); \
      float kv2 = kv_dot(kb, __builtin_amdgcn_readlane(e_v, (J0) + 2), obase, kw0, kw1, kw2, kw3); \
      float kv3 = kv_dot(kb, __builtin_amdgcn_readlane(e_v, (J0) + 3), obase, kw0, kw1, kw2, kw3); \
      float p0, p1, p2, p3;                                                    \
      red4(xv[(J0) + 0] * ubr, xv[(J0) + 1] * ubr,                             \
           xv[(J0) + 2] * ubr, xv[(J0) + 3] * ubr, p0, p1, p2, p3);            \
      float l0 = ((J0) + 0 < cl) ? fmaf(p0, scale2, base2) : -INFINITY;        \
      float l1 = ((J0) + 1 < cl) ? fmaf(p1, scale2, base2) : -INFINITY;        \
      float l2 = ((J0) + 2 < cl) ? fmaf(p2, scale2, base2) : -INFINITY;        \
      float l3 = ((J0) + 3 < cl) ? fmaf(p3, scale2, base2) : -INFINITY;        \
      float cm = fmaxf(fmaxf(l0, l1), fmaxf(l2, l3));                          \
      float mn = fmaxf(m2, cm);                                                \
      float rsc = exp2_fast(m2 - mn);                                          \
      S *= rsc; acc *= rsc; m2 = mn;                                           \
      float ev0 = exp2_fast(l0 - m2);                                          \
      float ev1 = exp2_fast(l1 - m2);                                          \
      float ev2 = exp2_fast(l2 - m2);                                          \
      float ev3 = exp2_fast(l3 - m2);                                          \
      S += ev0 + ev1 + ev2 + ev3;                                              \
      acc = fmaf(ev0 * kv0, xv[(J0) + 0], acc);                                \
      acc = fmaf(ev1 * kv1, xv[(J0) + 1], acc);                                \
      acc = fmaf(ev2 * kv2, xv[(J0) + 2], acc);                                \
      acc = fmaf(ev3 * kv3, xv[(J0) + 3], acc);                                \
    }
    SUB4(0)
    if (cl > 4)  SUB4(4)
    if (cl > 8)  SUB4(8)
    if (cl > 12) SUB4(12)
    #undef SUB4
  }

  float invd = 1.0f / (S + 1e-6f);
  x1[t] = acc * invd;
  __syncthreads();
  // fiber mix: out[n,p=o,c] = sum_oo x1[oo,c]*fk[o,oo,c] + bias[c]  (0.25 in fk)
  float s2s = 0.f;
  #pragma unroll
  for (int oo = 0; oo < OO; ++oo)
    s2s = fmaf(x1[oo * CC + c], fkg[o * (OO * CC) + oo * CC + c], s2s);
  out[(size_t)n * (OO * CC) + t] = s2s + bias[c];
}

extern "C" void kernel_launch(void* const* d_in, const int* in_sizes, int n_in,
                              void* d_out, int out_size, void* d_ws, size_t ws_size,
                              hipStream_t stream) {
  const float* x    = (const float*)d_in[0];
  const float* kb   = (const float*)d_in[1];
  const float* fkb  = (const float*)d_in[2];
  const int*   ei   = (const int*)d_in[3];
  const float* kW   = (const float*)d_in[4];
  const float* fkW  = (const float*)d_in[5];
  const float* keyW = (const float*)d_in[6];
  const float* keyB = (const float*)d_in[7];
  const float* qryW = (const float*)d_in[8];
  const float* qryB = (const float*)d_in[9];
  const float* bias = (const float*)d_in[10];
  float* out = (float*)d_out;

  float* wsf  = (float*)d_ws;
  float* Mt   = wsf;                          // 4096
  float* aVec = Mt + 4096;                    // 64
  float* bVec = aVec + 64;                    // 64
  float* c0   = bVec + 64;                    // 1 (+63 pad)
  float* fk   = c0 + 64;                      // 1024
  // total 5312 floats = 21248 B (8B-aligned)
  long long* pairs = (long long*)(fk + 1024);   // EE * 8B
  int* counts    = (int*)(pairs + EE);          // 50000
  int* offsets   = counts + NN;                 // 50001

  hipMemsetAsync(counts, 0, (size_t)NN * sizeof(int), stream);

  prep_kernel<<<17, 256, 0, stream>>>(keyW, keyB, qryW, qryB, fkb, fkW, Mt, aVec, bVec, c0, fk);
  count_kernel<<<(EE + 255) / 256, 256, 0, stream>>>(ei, counts);
  scan_kernel<<<1, 1024, 0, stream>>>(counts, offsets, NN);
  fill_kernel<<<(EE + 255) / 256, 256, 0, stream>>>(ei, offsets, counts, pairs);
  mega_kernel<<<NN, 256, 0, stream>>>(x, Mt, aVec, bVec, c0, kb, kW, offsets, pairs,
                                      fk, bias, out);
}

// Round 11
// 420.583 us; speedup vs baseline: 1.8778x; 1.2723x over previous
//
#include <hip/hip_runtime.h>
#include <math.h>

#define NN 50000
#define EE 800000
#define OO 4
#define CC 64
#define KDD 16
#define KEYDD 128
#define CH 16  // gather window per chunk

typedef float v2f __attribute__((ext_vector_type(2)));

// Full-wave (64-lane) sum via DPP builtins (prologue only)
__device__ __forceinline__ float wave_red_sum(float v) {
  int x;
  x = __builtin_amdgcn_update_dpp(0, __float_as_int(v), 0x111, 0xf, 0xf, false);
  v += __int_as_float(x);
  x = __builtin_amdgcn_update_dpp(0, __float_as_int(v), 0x112, 0xf, 0xf, false);
  v += __int_as_float(x);
  x = __builtin_amdgcn_update_dpp(0, __float_as_int(v), 0x114, 0xf, 0xf, false);
  v += __int_as_float(x);
  x = __builtin_amdgcn_update_dpp(0, __float_as_int(v), 0x118, 0xf, 0xf, false);
  v += __int_as_float(x);
  x = __builtin_amdgcn_update_dpp(0, __float_as_int(v), 0x142, 0xa, 0xf, false);
  v += __int_as_float(x);
  x = __builtin_amdgcn_update_dpp(0, __float_as_int(v), 0x143, 0xc, 0xf, false);
  v += __int_as_float(x);
  return __int_as_float(__builtin_amdgcn_readlane(__float_as_int(v), 63));
}

// bare v_exp_f32: D = 2^x  (softmax runs in log2 domain)
__device__ __forceinline__ float exp2_fast(float x) {
  float r;
  asm("v_exp_f32 %0, %1" : "=v"(r) : "v"(x));
  return r;
}

// Batched reduction of FOUR 64-lane vectors -> four wave-uniform sums.
// permlane32_swap folds pairs; one asm block of 10 v_add_f32_dpp with the two
// independent chains interleaved (covers DPP wait-states). Totals at lanes 31/63.
__device__ __forceinline__ void red4(float q0, float q1, float q2, float q3,
                                     float& p0, float& p1, float& p2, float& p3) {
  asm("s_nop 1\n\tv_permlane32_swap_b32 %0, %1" : "+v"(q0), "+v"(q1));
  float ra = q0 + q1;
  asm("s_nop 1\n\tv_permlane32_swap_b32 %0, %1" : "+v"(q2), "+v"(q3));
  float rb = q2 + q3;
  asm("s_nop 1\n\t"
      "v_add_f32_dpp %0, %0, %0 row_shr:1 row_mask:0xf bank_mask:0xf bound_ctrl:0\n\t"
      "v_add_f32_dpp %1, %1, %1 row_shr:1 row_mask:0xf bank_mask:0xf bound_ctrl:0\n\t"
      "v_add_f32_dpp %0, %0, %0 row_shr:2 row_mask:0xf bank_mask:0xf bound_ctrl:0\n\t"
      "v_add_f32_dpp %1, %1, %1 row_shr:2 row_mask:0xf bank_mask:0xf bound_ctrl:0\n\t"
      "v_add_f32_dpp %0, %0, %0 row_shr:4 row_mask:0xf bank_mask:0xf bound_ctrl:0\n\t"
      "v_add_f32_dpp %1, %1, %1 row_shr:4 row_mask:0xf bank_mask:0xf bound_ctrl:0\n\t"
      "v_add_f32_dpp %0, %0, %0 row_shr:8 row_mask:0xf bank_mask:0xf bound_ctrl:0\n\t"
      "v_add_f32_dpp %1, %1, %1 row_shr:8 row_mask:0xf bank_mask:0xf bound_ctrl:0\n\t"
      "v_add_f32_dpp %0, %0, %0 row_bcast:15 row_mask:0xa bank_mask:0xf bound_ctrl:0\n\t"
      "v_add_f32_dpp %1, %1, %1 row_bcast:15 row_mask:0xa bank_mask:0xf bound_ctrl:0\n\t"
      "s_nop 0"
      : "+v"(ra), "+v"(rb));
  p0 = __int_as_float(__builtin_amdgcn_readlane(__float_as_int(ra), 31));
  p1 = __int_as_float(__builtin_amdgcn_readlane(__float_as_int(ra), 63));
  p2 = __int_as_float(__builtin_amdgcn_readlane(__float_as_int(rb), 31));
  p3 = __int_as_float(__builtin_amdgcn_readlane(__float_as_int(rb), 63));
}

// P0 (blocks 0..15): Mt[c2*64+c1] = sum_k keyW[k,c1]*qryW[k,c2] (transposed).
// Block 16: aVec/bVec/c0/fk (fk pre-scaled by 0.25).
__global__ void prep_kernel(const float* __restrict__ keyW, const float* __restrict__ keyB,
                            const float* __restrict__ qryW, const float* __restrict__ qryB,
                            const float* __restrict__ fkb, const float* __restrict__ fkw,
                            float* __restrict__ Mt, float* __restrict__ aVec,
                            float* __restrict__ bVec, float* __restrict__ c0,
                            float* __restrict__ fk) {
  __shared__ float qw[KEYDD * CC];   // 32 KB
  __shared__ float kws[KEYDD * 4];   // 2 KB
  int t = threadIdx.x, b = blockIdx.x;
  if (b < 16) {
    for (int i = t; i < KEYDD * CC; i += 256) qw[i] = qryW[i];
    for (int i = t; i < KEYDD * 4; i += 256) {
      int k = i >> 2, c1l = i & 3;
      kws[i] = keyW[k * CC + b * 4 + c1l];
    }
    __syncthreads();
    int c1l = t >> 6, c2 = t & 63;
    float s = 0.f;
    #pragma unroll 8
    for (int k = 0; k < KEYDD; ++k)
      s = fmaf(kws[k * 4 + c1l], qw[k * CC + c2], s);
    Mt[c2 * CC + b * 4 + c1l] = s;
  } else {
    if (t < CC) {
      float sa = 0.f, sb = 0.f;
      for (int k = 0; k < KEYDD; ++k) {
        sa = fmaf(keyB[k], qryW[k * CC + t], sa);
        sb = fmaf(qryB[k], keyW[k * CC + t], sb);
      }
      aVec[t] = sa; bVec[t] = sb;
    }
    if (t == 0) {
      float s = 0.f;
      for (int k = 0; k < KEYDD; ++k) s = fmaf(keyB[k], qryB[k], s);
      c0[0] = s;
    }
    for (int idx = t; idx < OO * OO * CC; idx += 256) {
      int p = idx >> 8, rem = idx & 255;
      int o = rem >> 6, c = rem & 63;
      float s = 0.f;
      #pragma unroll
      for (int kd = 0; kd < KDD; ++kd)
        s = fmaf(fkb[(p * OO + o) * KDD + kd], fkw[c * KDD + kd], s);
      fk[idx] = 0.25f * s;  // fold the 1/O normalization here
    }
  }
}

// K2a: CSR degree counts
__global__ void count_kernel(const int* __restrict__ ei, int* __restrict__ counts) {
  int e = blockIdx.x * 256 + threadIdx.x;
  if (e < EE) atomicAdd(&counts[ei[EE + e]], 1);
}

// K2b: 3-dispatch parallel exclusive scan over counts[NN] -> offsets[NN+1]
__global__ void scan1_kernel(const int* __restrict__ counts, int* __restrict__ incl,
                             int* __restrict__ bsum, int n) {
  __shared__ int buf[256];
  int t = threadIdx.x;
  int i = blockIdx.x * 256 + t;
  int v = (i < n) ? counts[i] : 0;
  buf[t] = v;
  __syncthreads();
  for (int off = 1; off < 256; off <<= 1) {
    int a = buf[t];
    int b2 = (t >= off) ? buf[t - off] : 0;
    __syncthreads();
    buf[t] = a + b2;
    __syncthreads();
  }
  if (i < n) incl[i] = buf[t];
  if (t == 255) bsum[blockIdx.x] = buf[255];
}
__global__ void scan2_kernel(const int* __restrict__ bsum, int* __restrict__ bbase, int nb) {
  __shared__ int buf[256];
  int t = threadIdx.x;
  int v = (t < nb) ? bsum[t] : 0;
  buf[t] = v;
  __syncthreads();
  for (int off = 1; off < 256; off <<= 1) {
    int a = buf[t];
    int b2 = (t >= off) ? buf[t - off] : 0;
    __syncthreads();
    buf[t] = a + b2;
    __syncthreads();
  }
  if (t < nb) bbase[t] = buf[t] - v;  // exclusive
}
__global__ void scan3_kernel(const int* __restrict__ counts, const int* __restrict__ incl,
                             const int* __restrict__ bbase, int* __restrict__ offsets, int n) {
  int i = blockIdx.x * 256 + threadIdx.x;
  if (i < n) {
    int oi = bbase[blockIdx.x] + incl[i];
    offsets[i] = oi - counts[i];
    if (i == n - 1) offsets[n] = oi;
  }
}

// K2c: fill CSR as packed (src<<32 | eid) pairs; reuses counts as cursor.
__global__ void fill_kernel(const int* __restrict__ ei, const int* __restrict__ offsets,
                            int* __restrict__ counts, long long* __restrict__ pairs) {
  int e = blockIdx.x * 256 + threadIdx.x;
  if (e < EE) {
    int d = ei[EE + e];
    int r = atomicSub(&counts[d], 1) - 1;
    int pos = offsets[d] + r;
    pairs[pos] = ((long long)ei[e] << 32) | (unsigned)e;
  }
}

// kv = dot16(kb[ej, o, :], kW[c, :]) via PACKED f32 math: 8 v_pk_fma_f32
// + 1 pk_add + 1 add (was 16 scalar v_fmac). Loads stay dwordx4.
__device__ __forceinline__ float kv_dot(const float* __restrict__ kb, int ej, int obase,
                                        float4 kw0, float4 kw1, float4 kw2, float4 kw3) {
  const float4* bp = reinterpret_cast<const float4*>(kb + ej * (OO * KDD) + obase);
  float4 b0 = bp[0], b1 = bp[1], b2 = bp[2], b3 = bp[3];
  v2f a0 = {0.f, 0.f}, a1 = {0.f, 0.f};
  #define P2(f4, i) (reinterpret_cast<const v2f*>(&(f4))[i])
  a0 = __builtin_elementwise_fma(P2(b0, 0), P2(kw0, 0), a0);
  a1 = __builtin_elementwise_fma(P2(b0, 1), P2(kw0, 1), a1);
  a0 = __builtin_elementwise_fma(P2(b1, 0), P2(kw1, 0), a0);
  a1 = __builtin_elementwise_fma(P2(b1, 1), P2(kw1, 1), a1);
  a0 = __builtin_elementwise_fma(P2(b2, 0), P2(kw2, 0), a0);
  a1 = __builtin_elementwise_fma(P2(b2, 1), P2(kw2, 1), a1);
  a0 = __builtin_elementwise_fma(P2(b3, 0), P2(kw3, 0), a0);
  a1 = __builtin_elementwise_fma(P2(b3, 1), P2(kw3, 1), a1);
  #undef P2
  v2f s = a0 + a1;
  return s.x + s.y;
}

// K3: MEGA — per node; fused ub, wave=o owns its (n,o) softmax+aggregation
// end-to-end, barrier-free edge loop (R8/R10 structure — no pinned pipeline).
// __launch_bounds__(256, 4): VGPR cap 128 (no spill risk; kernel needs ~60) but
// RELAXES the allocator's occupancy target so the scheduler hoists the 16
// x-gathers up front. R10's unbounded build register-minimized to VGPR=28 for
// 8 waves/SIMD, sinking the gathers (MLP=4, VALUBusy 53%): trade waves for MLP.
// R4 NOTE: (256,8) capped VGPR at 64 -> spilled -> 4x regress; 128 is safe.
__global__ __launch_bounds__(256, 4) void mega_kernel(
    const float* __restrict__ x, const float* __restrict__ Mt,
    const float* __restrict__ aVec, const float* __restrict__ bVec,
    const float* __restrict__ c0p, const float* __restrict__ kb,
    const float* __restrict__ kW, const int* __restrict__ offsets,
    const long long* __restrict__ pairs, const float* __restrict__ fkg,
    const float* __restrict__ bias, float* __restrict__ out) {
  __shared__ float xs[OO * CC];
  __shared__ float x1[OO * CC];
  int n = blockIdx.x;
  int t = threadIdx.x;
  int o = __builtin_amdgcn_readfirstlane(t >> 6);
  int c = t & 63;
  const float scale2 = 0.12751541050862828f;  // (1/sqrt(128)) * log2(e)
  int js = offsets[n], je = offsets[n + 1];
  int deg = je - js;

  float xown = x[(size_t)n * (OO * CC) + t];
  xs[t] = xown;
  __syncthreads();

  int lane16 = c & 15;
  long long pr = 0;
  if (deg > 0) pr = pairs[js + min(lane16, deg - 1)];  // chunk-0 head, in flight early

  // ub = Mt^T x + bVec (independent of pr -> hides the pairs-load latency)
  float ubr = 0.f;
  #pragma unroll 8
  for (int c2 = 0; c2 < CC; ++c2)
    ubr = fmaf(Mt[c2 * CC + c], xs[o * CC + c2], ubr);
  ubr += bVec[c];
  float base2 = (wave_red_sum(aVec[c] * xown) + c0p[0]) * scale2;

  const float4* kwp = reinterpret_cast<const float4*>(kW + c * KDD);
  float4 kw0 = kwp[0], kw1 = kwp[1], kw2 = kwp[2], kw3 = kwp[3];
  int obase = o * KDD;

  float m2 = -INFINITY, S = 0.f, acc = 0.f;

  for (int cs = 0; cs < deg; cs += CH) {
    int cl = deg - cs; if (cl > CH) cl = CH;  // wave-uniform
    int e_v = (int)((unsigned long long)pr & 0xffffffffu);
    int s_v = (int)(pr >> 32);
    float xv[CH];
    // 1) x-row gathers (uniform row base via readlane)
    #pragma unroll
    for (int j = 0; j < CH; ++j) {
      int sj = __builtin_amdgcn_readlane(s_v, j);
      xv[j] = x[(size_t)(sj * OO + o) * CC + c];
    }
    // 2) prefetch next chunk's pairs
    int ns = cs + CH;
    if (ns < deg) {
      int ncl = deg - ns;
      pr = pairs[js + ns + min(lane16, ncl - 1)];
    }
    // 3) compute in 4-edge sub-blocks
    #define SUB4(J0)                                                           \
    {                                                                          \
      float kv0 = kv_dot(kb, __builtin_amdgcn_readlane(e_v, (J0) + 0), obase, kw0, kw1, kw2, kw3); \
      float kv1 = kv_dot(kb, __builtin_amdgcn_readlane(e_v, (J0) + 1), obase, kw0, kw1, kw2, kw3); \
      float kv2 = kv_dot(kb, __builtin_amdgcn_readlane(e_v, (J0) + 2), obase, kw0, kw1, kw2, kw3); \
      float kv3 = kv_dot(kb, __builtin_amdgcn_readlane(e_v, (J0) + 3), obase, kw0, kw1, kw2, kw3); \
      float p0, p1, p2, p3;                                                    \
      red4(xv[(J0) + 0] * ubr, xv[(J0) + 1] * ubr,                             \
           xv[(J0) + 2] * ubr, xv[(J0) + 3] * ubr, p0, p1, p2, p3);            \
      float l0 = ((J0) + 0 < cl) ? fmaf(p0, scale2, base2) : -INFINITY;        \
      float l1 = ((J0) + 1 < cl) ? fmaf(p1, scale2, base2) : -INFINITY;        \
      float l2 = ((J0) + 2 < cl) ? fmaf(p2, scale2, base2) : -INFINITY;        \
      float l3 = ((J0) + 3 < cl) ? fmaf(p3, scale2, base2) : -INFINITY;        \
      float cm = fmaxf(fmaxf(l0, l1), fmaxf(l2, l3));                          \
      if (cm > m2) {                                                           \
        float rsc = exp2_fast(m2 - cm);                                        \
        S *= rsc; acc *= rsc; m2 = cm;                                         \
      }                                                                        \
      float ev0 = exp2_fast(l0 - m2);                                          \
      float ev1 = exp2_fast(l1 - m2);                                          \
      float ev2 = exp2_fast(l2 - m2);                                          \
      float ev3 = exp2_fast(l3 - m2);                                          \
      S += (ev0 + ev1) + (ev2 + ev3);                                          \
      acc = fmaf(ev0 * kv0, xv[(J0) + 0], acc);                                \
      acc = fmaf(ev1 * kv1, xv[(J0) + 1], acc);                                \
      acc = fmaf(ev2 * kv2, xv[(J0) + 2], acc);                                \
      acc = fmaf(ev3 * kv3, xv[(J0) + 3], acc);                                \
    }
    SUB4(0)
    if (cl > 4)  SUB4(4)
    if (cl > 8)  SUB4(8)
    if (cl > 12) SUB4(12)
    #undef SUB4
  }

  float invd = 1.0f / (S + 1e-6f);
  x1[t] = acc * invd;
  __syncthreads();
  // fiber mix: out[n,p=o,c] = sum_oo x1[oo,c]*fk[o,oo,c] + bias[c]  (0.25 in fk)
  float s2s = 0.f;
  #pragma unroll
  for (int oo = 0; oo < OO; ++oo)
    s2s = fmaf(x1[oo * CC + c], fkg[o * (OO * CC) + oo * CC + c], s2s);
  out[(size_t)n * (OO * CC) + t] = s2s + bias[c];
}

extern "C" void kernel_launch(void* const* d_in, const int* in_sizes, int n_in,
                              void* d_out, int out_size, void* d_ws, size_t ws_size,
                              hipStream_t stream) {
  const float* x    = (const float*)d_in[0];
  const float* kb   = (const float*)d_in[1];
  const float* fkb  = (const float*)d_in[2];
  const int*   ei   = (const int*)d_in[3];
  const float* kW   = (const float*)d_in[4];
  const float* fkW  = (const float*)d_in[5];
  const float* keyW = (const float*)d_in[6];
  const float* keyB = (const float*)d_in[7];
  const float* qryW = (const float*)d_in[8];
  const float* qryB = (const float*)d_in[9];
  const float* bias = (const float*)d_in[10];
  float* out = (float*)d_out;

  const int NB = (NN + 255) / 256;  // 196 scan blocks

  float* wsf  = (float*)d_ws;
  float* Mt   = wsf;                          // 4096
  float* aVec = Mt + 4096;                    // 64
  float* bVec = aVec + 64;                    // 64
  float* c0   = bVec + 64;                    // 1 (+63 pad)
  float* fk   = c0 + 64;                      // 1024
  long long* pairs = (long long*)(fk + 1024); // EE * 8B (8B-aligned: 5312 floats before)
  int* counts    = (int*)(pairs + EE);        // 50000
  int* offsets   = counts + NN;               // 50001
  int* incl      = offsets + NN + 1;          // 50000
  int* bsum      = incl + NN;                 // NB
  int* bbase     = bsum + 256;                // NB

  hipMemsetAsync(counts, 0, (size_t)NN * sizeof(int), stream);

  prep_kernel<<<17, 256, 0, stream>>>(keyW, keyB, qryW, qryB, fkb, fkW, Mt, aVec, bVec, c0, fk);
  count_kernel<<<(EE + 255) / 256, 256, 0, stream>>>(ei, counts);
  scan1_kernel<<<NB, 256, 0, stream>>>(counts, incl, bsum, NN);
  scan2_kernel<<<1, 256, 0, stream>>>(bsum, bbase, NB);
  scan3_kernel<<<NB, 256, 0, stream>>>(counts, incl, bbase, offsets, NN);
  fill_kernel<<<(EE + 255) / 256, 256, 0, stream>>>(ei, offsets, counts, pairs);
  mega_kernel<<<NN, 256, 0, stream>>>(x, Mt, aVec, bVec, c0, kb, kW, offsets, pairs,
                                      fk, bias, out);
}